// Round 2
// baseline (1081.380 us; speedup 1.0000x reference)
//
#include <hip/hip_runtime.h>

#define B_   4
#define NB_  128
#define BS_  128
#define C_   256
#define H_   8
#define KL_  129   // BS_+1
#define SCALE_ 0.17677669529663687f

typedef unsigned short u16;
typedef unsigned int   u32;

__device__ __forceinline__ float bf16tof(u16 u) {
  union { u32 i; float f; } v; v.i = ((u32)u) << 16; return v.f;
}
__device__ __forceinline__ u16 ftobf16(float f) {
  union { float f; u32 i; } v; v.f = f;
  u32 b = v.i + 0x7FFFu + ((v.i >> 16) & 1u);
  return (u16)(b >> 16);
}
__device__ __forceinline__ void unpack8(uint4 u, float* d) {
  d[0] = bf16tof((u16)(u.x & 0xffff)); d[1] = bf16tof((u16)(u.x >> 16));
  d[2] = bf16tof((u16)(u.y & 0xffff)); d[3] = bf16tof((u16)(u.y >> 16));
  d[4] = bf16tof((u16)(u.z & 0xffff)); d[5] = bf16tof((u16)(u.z >> 16));
  d[6] = bf16tof((u16)(u.w & 0xffff)); d[7] = bf16tof((u16)(u.w >> 16));
}

// ---------- kernel 1: per-block mean (block node) ----------
__global__ __launch_bounds__(256) void mean_kernel(const float* __restrict__ x,
                                                   float* __restrict__ bn) {
  const int blk = blockIdx.x;          // b*NB_ + n
  const int c = threadIdx.x;
  const float* p = x + (size_t)blk * BS_ * C_ + c;
  float s = 0.f;
  #pragma unroll 4
  for (int r = 0; r < BS_; ++r) s += p[(size_t)r * C_];
  bn[(size_t)blk * C_ + c] = s * (1.0f / BS_);
}

// ---------- kernels 2 & 4: tiled GEMM, out[M][NS] = A'[M][256] @ W + bias ----
// MAP: A' row g -> blk=g/129, r=g%129; r<128 from x (f32), r==128 from bn (f32).
// !MAP: A is bf16 with 256 cols.  OBF16: store bf16, else f32.
template<bool MAP, int NS, bool OBF16>
__global__ __launch_bounds__(256) void gemm_kernel(const void* __restrict__ Av,
      const float* __restrict__ Bn, const float* __restrict__ W,
      const float* __restrict__ bias, void* __restrict__ outv) {
  __shared__ float As[16][68];   // transposed A tile (padded)
  __shared__ float Bs[16][64];
  const int tid = threadIdx.x;
  const int row0 = blockIdx.x * 64;
  const int col0 = blockIdx.y * 64;
  const int arow = tid >> 2;           // 0..63
  const int akq  = (tid & 3) << 2;     // 0,4,8,12
  const float* aptr_f = nullptr;
  const u16*   aptr_b = nullptr;
  if constexpr (MAP) {
    const int g = row0 + arow;
    const int blk = g / KL_;
    const int r = g - blk * KL_;
    aptr_f = (r < BS_) ? ((const float*)Av + ((size_t)blk * BS_ + r) * C_)
                       : (Bn + (size_t)blk * C_);
  } else {
    aptr_b = (const u16*)Av + (size_t)(row0 + arow) * C_;
  }
  const int brow = tid >> 4;           // 0..15
  const int bcol = (tid & 15) << 2;
  const int tx = tid & 15, ty = tid >> 4;
  float acc[4][4] = {};
  for (int k0 = 0; k0 < C_; k0 += 16) {
    if constexpr (MAP) {
      const float4 a4 = *(const float4*)(aptr_f + k0 + akq);
      As[akq + 0][arow] = a4.x; As[akq + 1][arow] = a4.y;
      As[akq + 2][arow] = a4.z; As[akq + 3][arow] = a4.w;
    } else {
      const uint2 u = *(const uint2*)(aptr_b + k0 + akq);
      As[akq + 0][arow] = bf16tof((u16)(u.x & 0xffff));
      As[akq + 1][arow] = bf16tof((u16)(u.x >> 16));
      As[akq + 2][arow] = bf16tof((u16)(u.y & 0xffff));
      As[akq + 3][arow] = bf16tof((u16)(u.y >> 16));
    }
    *(float4*)(&Bs[brow][bcol]) =
        *(const float4*)(W + (size_t)(k0 + brow) * NS + col0 + bcol);
    __syncthreads();
    #pragma unroll
    for (int kk = 0; kk < 16; ++kk) {
      const float4 av = *(const float4*)(&As[kk][ty << 2]);
      const float4 bv = *(const float4*)(&Bs[kk][tx << 2]);
      acc[0][0] += av.x * bv.x; acc[0][1] += av.x * bv.y;
      acc[0][2] += av.x * bv.z; acc[0][3] += av.x * bv.w;
      acc[1][0] += av.y * bv.x; acc[1][1] += av.y * bv.y;
      acc[1][2] += av.y * bv.z; acc[1][3] += av.y * bv.w;
      acc[2][0] += av.z * bv.x; acc[2][1] += av.z * bv.y;
      acc[2][2] += av.z * bv.z; acc[2][3] += av.z * bv.w;
      acc[3][0] += av.w * bv.x; acc[3][1] += av.w * bv.y;
      acc[3][2] += av.w * bv.z; acc[3][3] += av.w * bv.w;
    }
    __syncthreads();
  }
  const float4 bb = *(const float4*)(bias + col0 + (tx << 2));
  #pragma unroll
  for (int i = 0; i < 4; ++i) {
    float4 o;
    o.x = acc[i][0] + bb.x; o.y = acc[i][1] + bb.y;
    o.z = acc[i][2] + bb.z; o.w = acc[i][3] + bb.w;
    const size_t row = (size_t)(row0 + (ty << 2) + i);
    if constexpr (OBF16) {
      u16* ob = (u16*)outv + row * NS + col0 + (tx << 2);
      uint2 p;
      p.x = (u32)ftobf16(o.x) | ((u32)ftobf16(o.y) << 16);
      p.y = (u32)ftobf16(o.z) | ((u32)ftobf16(o.w) << 16);
      *(uint2*)ob = p;
    } else {
      *(float4*)((float*)outv + row * NS + col0 + (tx << 2)) = o;
    }
  }
}

// ---------- kernel 3: fused block attention ----------
// One WG per (b,block). LDS: K_h,V_h f32 slices (33 KB). Thread pair per q-row
// splits the 129-key range; sadd/gate computed on the fly from mask/ef/w_gate.
__global__ __launch_bounds__(256) void attn_kernel(const u16* __restrict__ qkv,
      const int* __restrict__ mask, const float* __restrict__ ef,
      const float* __restrict__ wg_, const float* __restrict__ bg,
      u16* __restrict__ ao) {
  __shared__ float ks[KL_][32];                // 16512 B
  __shared__ float vs[KL_][32];                // 16512 B
  const int wgi = blockIdx.x;                  // b*NB_ + n
  const int n = wgi & (NB_ - 1);
  const int tid = threadIdx.x;
  const u16* qkv_blk = qkv + (size_t)wgi * KL_ * 768;
  const int qrow = tid >> 1;
  const int kh = tid & 1;
  const int kbeg = kh ? 65 : 0;
  const int kend = kh ? KL_ : 65;
  const int*   mrow = mask + ((size_t)n * BS_ + qrow) * KL_;
  const float* erow = ef + (((size_t)n * BS_ + qrow) * KL_) * 4;

  for (int h = 0; h < H_; ++h) {
    // stage K_h, V_h (bf16 -> f32)
    for (int i = tid; i < KL_ * 4; i += 256) {
      const int r = i >> 2, jq = i & 3;        // jq: which 8-elem group
      const u16* rp = qkv_blk + (size_t)r * 768 + h * 32;
      const uint4 ku = *(const uint4*)(rp + 256 + jq * 8);
      const uint4 vu = *(const uint4*)(rp + 512 + jq * 8);
      unpack8(ku, &ks[r][jq * 8]);
      unpack8(vu, &vs[r][jq * 8]);
    }
    __syncthreads();

    float qf[32];
    const u16* qp = qkv_blk + (size_t)qrow * 768 + h * 32;
    #pragma unroll
    for (int jj = 0; jj < 4; ++jj) {
      const uint4 qu = *(const uint4*)(qp + jj * 8);
      unpack8(qu, &qf[jj * 8]);
    }
    const float wgc0 = wg_[h], wgc1 = wg_[8 + h], wgc2 = wg_[16 + h],
                wgc3 = wg_[24 + h], bgh = bg[h];

    float ssum = 0.f;
    float num[32], gac[32];
    #pragma unroll
    for (int j = 0; j < 32; ++j) { num[j] = 0.f; gac[j] = 0.f; }

    for (int k = kbeg; k < kend; ++k) {
      float d = 0.f;
      #pragma unroll
      for (int j = 0; j < 32; ++j) d += qf[j] * ks[k][j];
      const int m = mrow[k];
      float4 e = *(const float4*)(erow + (size_t)k * 4);
      const bool sp = (k == BS_) | (k == qrow);
      if (sp) { e.x = 0.f; e.y = 0.f; e.z = 0.f; e.w = 1.f; }
      const float sadd = m ? e.w : -1e30f;
      const float gt = m ? (e.x * wgc0 + e.y * wgc1 + e.z * wgc2
                            + e.w * wgc3 + bgh) : 0.f;
      const float w = __expf(d * SCALE_ + sadd);
      ssum += w;
      #pragma unroll
      for (int j = 0; j < 32; ++j) {
        const float vv = vs[k][j];
        num[j] += w * vv;
        gac[j] += gt * vv;
      }
    }
    ssum += __shfl_xor(ssum, 1);
    #pragma unroll
    for (int j = 0; j < 32; ++j) {
      num[j] += __shfl_xor(num[j], 1);
      gac[j] += __shfl_xor(gac[j], 1);
    }
    const float inv = 1.0f / ssum;
    const int base = kh * 16;
    u16* aop = ao + (((size_t)wgi * BS_ + qrow) * C_ + h * 32 + base);
    u32 p[8];
    #pragma unroll
    for (int j = 0; j < 8; ++j) {
      const float o0 = num[base + 2*j]     * inv + gac[base + 2*j];
      const float o1 = num[base + 2*j + 1] * inv + gac[base + 2*j + 1];
      p[j] = (u32)ftobf16(o0) | ((u32)ftobf16(o1) << 16);
    }
    uint4 s0; s0.x = p[0]; s0.y = p[1]; s0.z = p[2]; s0.w = p[3];
    uint4 s1; s1.x = p[4]; s1.y = p[5]; s1.z = p[6]; s1.w = p[7];
    *(uint4*)(aop)     = s0;
    *(uint4*)(aop + 8) = s1;
    __syncthreads();
  }
}

extern "C" void kernel_launch(void* const* d_in, const int* in_sizes, int n_in,
                              void* d_out, int out_size, void* d_ws, size_t ws_size,
                              hipStream_t stream) {
  (void)in_sizes; (void)n_in; (void)out_size; (void)ws_size;
  const float* x      = (const float*)d_in[0];
  const int*   mask   = (const int*)  d_in[1];
  const float* ef     = (const float*)d_in[2];
  const float* w_qkv  = (const float*)d_in[3];
  const float* b_qkv  = (const float*)d_in[4];
  const float* w_proj = (const float*)d_in[5];
  const float* b_proj = (const float*)d_in[6];
  const float* w_gate = (const float*)d_in[7];
  const float* b_gate = (const float*)d_in[8];
  float* out = (float*)d_out;
  char* ws = (char*)d_ws;

  // workspace layout (bytes), total 135,528,448
  float* bn  = (float*)(ws);                 //       524,288
  u16*   qkv = (u16*)(ws + 524288);          //   101,449,728
  u16*   ao  = (u16*)(ws + 101974016);       //    33,554,432

  mean_kernel<<<B_ * NB_, 256, 0, stream>>>(x, bn);
  gemm_kernel<true, 768, true>
      <<<dim3((B_ * NB_ * KL_) / 64, 768 / 64), 256, 0, stream>>>(
      x, bn, w_qkv, b_qkv, qkv);
  attn_kernel<<<B_ * NB_, 256, 0, stream>>>(qkv, mask, ef, w_gate, b_gate, ao);
  gemm_kernel<false, 256, false>
      <<<dim3((B_ * NB_ * BS_) / 64, 256 / 64), 256, 0, stream>>>(
      ao, nullptr, w_proj, b_proj, out);
}